// Round 9
// baseline (558.860 us; speedup 1.0000x reference)
//
#include <hip/hip_runtime.h>
#include <hip/hip_cooperative_groups.h>
#include <math.h>

namespace cg = cooperative_groups;

// SimpleGCN: h1 = relu(GCN(x,W1,b1)); h2 = relu(GCN(h1,W2,b2));
// g = mean(h2, axis=0); out = (g@Wr + br) -> 128 fp32.
// GCN(x,W,b)[d] = dinv[d]*( sum_{s in N(d)} y[s] + y[d] ) + b,
//   y = dinv * (x@W), dinv[i] = (1+indeg[i])^-0.5.
//
// R8 post-mortem: no dominant dispatch; 13 launches x ~3us gaps + h1/pbuf
// round-trips are the remaining cost. R9: structural collapse to 5 dispatches:
//  1) ONE cooperative build kernel (hist -> colscan -> scanb -> scatter ->
//     per-bucket counting sort; 4 grid syncs; also zeroes g),
//  2) gemm1,
//  3) agg1 with gemm2 fused via LDS (16 nodes/block, lane=(node,f4col),
//     unroll-8 gathers, no cross-lane reduce; h tile 4KB + W2 16KB in LDS),
//  4) agg2 with mean fused (xor-butterfly + 64 g-atomics per block),
//  5) readout.

#define MAXNB 1024  // NB = ceil(n/64) <= 1024 (n <= 65536)
#define GB 256      // build grid (blocks); also #chunks

__global__ __launch_bounds__(256) void k_build(const int* __restrict__ src,
                                               const int* __restrict__ dst,
                                               int* __restrict__ histmat,
                                               int* __restrict__ tot,
                                               int* __restrict__ bstart,
                                               int* __restrict__ staged,
                                               unsigned short* __restrict__ csr,
                                               int* __restrict__ offsets,
                                               float* __restrict__ dinv,
                                               float* __restrict__ g,
                                               int E, int n, int NB, int CH2) {
    cg::grid_group grid = cg::this_grid();
    __shared__ int sm[MAXNB];
    __shared__ int sc[256];
    __shared__ int carry;
    __shared__ int cnt[64], pref[64], cur[64];
    int t = threadIdx.x, b = blockIdx.x;
    if (b == 0 && t < 64) g[t] = 0.f;   // replaces memset launch

    // P1: per-chunk LDS histogram over 64-node buckets
    for (int k = t; k < NB; k += 256) sm[k] = 0;
    __syncthreads();
    int base = b * CH2;
    int lim = min(E, base + CH2);
    for (int e = base + t; e < lim; e += 256) atomicAdd(&sm[dst[e] >> 6], 1);
    __syncthreads();
    for (int k = t; k < NB; k += 256) histmat[(size_t)b * NB + k] = sm[k];
    grid.sync();

    // P2a: per-bucket column scan over the GB chunks (coalesced, unroll-8)
    int kk = b * 256 + t;
    if (kk < NB) {
        int run = 0;
        for (int c = 0; c < GB; c += 8) {
            int v[8];
#pragma unroll
            for (int u = 0; u < 8; u++) v[u] = histmat[(size_t)(c + u) * NB + kk];
#pragma unroll
            for (int u = 0; u < 8; u++) {
                int x = v[u];
                histmat[(size_t)(c + u) * NB + kk] = run;
                run += x;
            }
        }
        tot[kk] = run;
    }
    grid.sync();

    // P2b: block 0 scans NB bucket totals -> bstart
    if (b == 0) {
        if (t == 0) carry = 0;
        __syncthreads();
        int nchunk = (NB + 255) / 256;
        for (int c = 0; c < nchunk; c++) {
            int idx = c * 256 + t;
            int v = (idx < NB) ? tot[idx] : 0;
            sc[t] = v;
            __syncthreads();
            for (int off = 1; off < 256; off <<= 1) {
                int x = (t >= off) ? sc[t - off] : 0;
                __syncthreads();
                sc[t] += x;
                __syncthreads();
            }
            if (idx < NB) bstart[idx] = sc[t] - v + carry;
            __syncthreads();
            if (t == 0) carry += sc[255];
            __syncthreads();
        }
        if (t == 0) { bstart[NB] = E; offsets[n] = E; }
    }
    grid.sync();

    // P3: scatter into per-(chunk,bucket) contiguous runs (no global atomics)
    for (int k = t; k < NB; k += 256)
        sm[k] = bstart[k] + histmat[(size_t)b * NB + k];
    __syncthreads();
    for (int e = base + t; e < lim; e += 256) {
        int d = dst[e];
        int pos = atomicAdd(&sm[d >> 6], 1);
        staged[pos] = (src[e] << 6) | (d & 63);
    }
    grid.sync();

    // P4: per-bucket counting sort -> node-granular ushort CSR + offsets/dinv
    for (int k = b; k < NB; k += gridDim.x) {
        if (t < 64) cnt[t] = 0;
        __syncthreads();
        int beg = bstart[k], end = bstart[k + 1];
        for (int e = beg + t; e < end; e += 256) atomicAdd(&cnt[staged[e] & 63], 1);
        __syncthreads();
        if (t == 0) {
            int run = 0;
            for (int i = 0; i < 64; i++) { pref[i] = run; run += cnt[i]; }
        }
        __syncthreads();
        if (t < 64) {
            cur[t] = pref[t];
            int node = k * 64 + t;
            if (node < n) {
                offsets[node] = beg + pref[t];
                dinv[node] = 1.0f / sqrtf((float)(cnt[t] + 1));  // + self-loop
            }
        }
        __syncthreads();
        for (int e = beg + t; e < end; e += 256) {
            int pk = staged[e];
            int p = atomicAdd(&cur[pk & 63], 1);
            csr[beg + p] = (unsigned short)(pk >> 6);
        }
        __syncthreads();
    }
}

// Y[i,:] = dinv[i] * (X[i,:] @ W). 16 rows/block, 4 rows/wave.
__global__ __launch_bounds__(256) void k_gemm_scale(const float* __restrict__ X,
                                                    const float* __restrict__ W,
                                                    const float* __restrict__ dinv,
                                                    float* __restrict__ Y, int n) {
    __shared__ float Ws[64 * 64];
    __shared__ float xs[16][64];
    int t = threadIdx.x, w = t >> 6, f = t & 63;
    const float4* W4 = (const float4*)W;
    float4* Ws4 = (float4*)Ws;
#pragma unroll
    for (int j = 0; j < 4; j++) Ws4[t + 256 * j] = W4[t + 256 * j];
    int r0 = blockIdx.x * 16;
#pragma unroll
    for (int i = 0; i < 4; i++) {
        int r = r0 + w * 4 + i;
        xs[w * 4 + i][f] = (r < n) ? X[(size_t)r * 64 + f] : 0.f;
    }
    __syncthreads();
    float acc[4] = {0.f, 0.f, 0.f, 0.f};
#pragma unroll 8
    for (int k = 0; k < 64; k++) {
        float wv = Ws[k * 64 + f];
#pragma unroll
        for (int i = 0; i < 4; i++) acc[i] += xs[w * 4 + i][k] * wv;
    }
#pragma unroll
    for (int i = 0; i < 4; i++) {
        int r = r0 + w * 4 + i;
        if (r < n) Y[(size_t)r * 64 + f] = dinv[r] * acc[i];
    }
}

__device__ __forceinline__ float4 xor4(float4 a, int m) {
    a.x += __shfl_xor(a.x, m);
    a.y += __shfl_xor(a.y, m);
    a.z += __shfl_xor(a.z, m);
    a.w += __shfl_xor(a.w, m);
    return a;
}

// Layer-1 aggregate + fused GEMM2. 16 nodes/block; lane l = i*16+c
// (i = node-in-wave, c = float4 column). Per node: unroll-8 row gathers
// (8 KB/wave in flight), acc complete per lane (no reduce). h tile -> LDS,
// then R2-style 4-rows/wave GEMM vs LDS W2: y2 = dinv * (h1 @ W2).
__global__ __launch_bounds__(256) void k_agg_fuse(const float* __restrict__ Y,
                                                  const float* __restrict__ dinv,
                                                  const float* __restrict__ bias,
                                                  const int* __restrict__ offsets,
                                                  const unsigned short* __restrict__ csr,
                                                  const float* __restrict__ W2,
                                                  float* __restrict__ Yout, int n) {
    __shared__ float Ws[64 * 64];   // 16 KB
    __shared__ float hs[16 * 64];   // 4 KB
    int t = threadIdx.x, w = t >> 6, l = t & 63;
    int i = l >> 4, c = l & 15;
    const float4* W4 = (const float4*)W2;
    float4* Ws4 = (float4*)Ws;
#pragma unroll
    for (int j = 0; j < 4; j++) Ws4[t + 256 * j] = W4[t + 256 * j];
    int base = blockIdx.x * 16;
    int node = base + w * 4 + i;
    bool valid = node < n;
    const float4* Y4 = (const float4*)Y;
    float4 acc = make_float4(0.f, 0.f, 0.f, 0.f);
    if (valid) {
        acc = Y4[(size_t)node * 16 + c];  // self-loop term
        int beg = offsets[node];
        int deg = offsets[node + 1] - beg;
        for (int e0 = 0; e0 < deg; e0 += 8) {
#pragma unroll
            for (int u = 0; u < 8; u++) {
                int e = e0 + u;
                if (e < deg) {
                    int s = csr[beg + e];
                    float4 v = Y4[(size_t)s * 16 + c];
                    acc.x += v.x; acc.y += v.y; acc.z += v.z; acc.w += v.w;
                }
            }
        }
        float dv = dinv[node];
        float4 b4 = ((const float4*)bias)[c];
        acc.x = fmaxf(dv * acc.x + b4.x, 0.f);
        acc.y = fmaxf(dv * acc.y + b4.y, 0.f);
        acc.z = fmaxf(dv * acc.z + b4.z, 0.f);
        acc.w = fmaxf(dv * acc.w + b4.w, 0.f);
    } else {
        acc = make_float4(0.f, 0.f, 0.f, 0.f);
    }
    ((float4*)hs)[(w * 4 + i) * 16 + c] = acc;
    __syncthreads();
    // GEMM epilogue: y2[r][f] = dinv[r] * sum_k h[r][k] * W2[k][f]
    float a2[4] = {0.f, 0.f, 0.f, 0.f};
    int f = l;
#pragma unroll 8
    for (int k = 0; k < 64; k++) {
        float wv = Ws[k * 64 + f];
#pragma unroll
        for (int r = 0; r < 4; r++) a2[r] += hs[(w * 4 + r) * 64 + k] * wv;
    }
#pragma unroll
    for (int r = 0; r < 4; r++) {
        int rr = base + w * 4 + r;
        if (rr < n) Yout[(size_t)rr * 64 + f] = dinv[rr] * a2[r];
    }
}

// Layer-2 aggregate + fused mean: same gather; relu'd h reduced over the
// block's 16 nodes (xor butterflies + LDS) -> 64 atomicAdds into g.
__global__ __launch_bounds__(256) void k_agg_pool(const float* __restrict__ Y,
                                                  const float* __restrict__ dinv,
                                                  const float* __restrict__ bias,
                                                  const int* __restrict__ offsets,
                                                  const unsigned short* __restrict__ csr,
                                                  float* __restrict__ g, int n) {
    __shared__ float4 sm4[4][16];
    int t = threadIdx.x, w = t >> 6, l = t & 63;
    int i = l >> 4, c = l & 15;
    int node = blockIdx.x * 16 + w * 4 + i;
    bool valid = node < n;
    const float4* Y4 = (const float4*)Y;
    float4 acc = make_float4(0.f, 0.f, 0.f, 0.f);
    if (valid) {
        acc = Y4[(size_t)node * 16 + c];  // self-loop term
        int beg = offsets[node];
        int deg = offsets[node + 1] - beg;
        for (int e0 = 0; e0 < deg; e0 += 8) {
#pragma unroll
            for (int u = 0; u < 8; u++) {
                int e = e0 + u;
                if (e < deg) {
                    int s = csr[beg + e];
                    float4 v = Y4[(size_t)s * 16 + c];
                    acc.x += v.x; acc.y += v.y; acc.z += v.z; acc.w += v.w;
                }
            }
        }
        float dv = dinv[node];
        float4 b4 = ((const float4*)bias)[c];
        acc.x = fmaxf(dv * acc.x + b4.x, 0.f);
        acc.y = fmaxf(dv * acc.y + b4.y, 0.f);
        acc.z = fmaxf(dv * acc.z + b4.z, 0.f);
        acc.w = fmaxf(dv * acc.w + b4.w, 0.f);
    } else {
        acc = make_float4(0.f, 0.f, 0.f, 0.f);
    }
    acc = xor4(acc, 16);  // reduce over the wave's 4 nodes (lane bits 4,5)
    acc = xor4(acc, 32);
    if (l < 16) sm4[w][l] = acc;
    __syncthreads();
    if (t < 16) {
        float4 a = sm4[0][t], b = sm4[1][t], d = sm4[2][t], e = sm4[3][t];
        atomicAdd(&g[t * 4 + 0], (a.x + b.x) + (d.x + e.x));
        atomicAdd(&g[t * 4 + 1], (a.y + b.y) + (d.y + e.y));
        atomicAdd(&g[t * 4 + 2], (a.z + b.z) + (d.z + e.z));
        atomicAdd(&g[t * 4 + 3], (a.w + b.w) + (d.w + e.w));
    }
}

__global__ void k_readout(const float* __restrict__ g, const float* __restrict__ Wr,
                          const float* __restrict__ br, float* __restrict__ out,
                          float invn) {
    __shared__ float gl[64];
    int t = threadIdx.x;
    if (t < 64) gl[t] = g[t] * invn;
    __syncthreads();
    float acc = br[t];
#pragma unroll
    for (int k = 0; k < 64; k++) acc += gl[k] * Wr[k * 128 + t];
    out[t] = acc;
}

extern "C" void kernel_launch(void* const* d_in, const int* in_sizes, int n_in,
                              void* d_out, int out_size, void* d_ws, size_t ws_size,
                              hipStream_t stream) {
    const float* x  = (const float*)d_in[0];
    const int*   ei = (const int*)d_in[1];   // int32 on device (JAX x64 off)
    const float* W1 = (const float*)d_in[2];
    const float* b1 = (const float*)d_in[3];
    const float* W2 = (const float*)d_in[4];
    const float* b2 = (const float*)d_in[5];
    const float* Wr = (const float*)d_in[6];
    const float* br = (const float*)d_in[7];
    float* out = (float*)d_out;

    int n = in_sizes[0] / 64;   // 50000
    int E = in_sizes[1] / 2;    // 800000
    const int* src = ei;
    const int* dst = ei + E;

    int NB  = (n + 63) / 64;       // 782 buckets of 64 nodes
    int CH2 = (E + GB - 1) / GB;   // edges per build block

    // workspace layout (~31 MB)
    char* p = (char*)d_ws;
    float* y1 = (float*)p;     p += (size_t)n * 64 * sizeof(float);
    float* y2 = (float*)p;     p += (size_t)n * 64 * sizeof(float);
    float* dinv = (float*)p;   p += (size_t)n * sizeof(float);
    float* g = (float*)p;      p += 64 * sizeof(float);
    int* staged = (int*)p;     p += (size_t)E * sizeof(int);
    int* offsets = (int*)p;    p += (size_t)(n + 1) * sizeof(int);
    int* histmat = (int*)p;    p += (size_t)GB * NB * sizeof(int);
    int* tot = (int*)p;        p += (size_t)NB * sizeof(int);
    int* bstart = (int*)p;     p += (size_t)(NB + 1) * sizeof(int);
    unsigned short* csr = (unsigned short*)p; p += (size_t)E * sizeof(unsigned short);

    void* bargs[] = {&src, &dst, &histmat, &tot, &bstart, &staged, &csr,
                     &offsets, &dinv, &g, &E, &n, &NB, &CH2};
    hipLaunchCooperativeKernel((void*)k_build, dim3(GB), dim3(256), bargs, 0, stream);

    int nblk = (n + 15) / 16;  // 3125
    k_gemm_scale<<<nblk, 256, 0, stream>>>(x, W1, dinv, y1, n);
    k_agg_fuse<<<nblk, 256, 0, stream>>>(y1, dinv, b1, offsets, csr, W2, y2, n);
    k_agg_pool<<<nblk, 256, 0, stream>>>(y2, dinv, b2, offsets, csr, g, n);
    k_readout<<<1, 128, 0, stream>>>(g, Wr, br, out, 1.0f / (float)n);
}

// Round 10
// 367.075 us; speedup vs baseline: 1.5225x; 1.5225x over previous
//
#include <hip/hip_runtime.h>
#include <hip/hip_cooperative_groups.h>
#include <math.h>

namespace cg = cooperative_groups;

// SimpleGCN: h1 = relu(GCN(x,W1,b1)); h2 = relu(GCN(h1,W2,b2));
// g = mean(h2, axis=0); out = (g@Wr + br) -> 128 fp32.
// GCN(x,W,b)[d] = dinv[d]*( sum_{s in N(d)} y[s] + y[d] ) + b,
//   y = dinv * (x@W), dinv[i] = (1+indeg[i])^-0.5.
//
// R9 post-mortem: putting 4 nodes in one wave made beg/deg per-lane vectors
// (divergent loop bounds) -> both aggregates collapsed to ~240us at 340GB/s.
// R10: aggregates reverted to the proven R6 structure — wave-per-node
// (beg/end wave-uniform in SGPRs), lane=(edge slot q, float4 col c),
// unroll-4 -> 16 row-gathers in flight/wave. Kept from R9: the single
// cooperative build kernel (hist->colscan->scanb->scatter->sort, 4 grid
// syncs, zeroes g) and ushort CSR indices. 7 dispatches total.

#define MAXNB 1024  // NB = ceil(n/64) <= 1024 (n <= 65536)
#define GB 256      // build grid (blocks); also #chunks

__global__ __launch_bounds__(256) void k_build(const int* __restrict__ src,
                                               const int* __restrict__ dst,
                                               int* __restrict__ histmat,
                                               int* __restrict__ tot,
                                               int* __restrict__ bstart,
                                               int* __restrict__ staged,
                                               unsigned short* __restrict__ csr,
                                               int* __restrict__ offsets,
                                               float* __restrict__ dinv,
                                               float* __restrict__ g,
                                               int E, int n, int NB, int CH2) {
    cg::grid_group grid = cg::this_grid();
    __shared__ int sm[MAXNB];
    __shared__ int sc[256];
    __shared__ int carry;
    __shared__ int cnt[64], pref[64], cur[64];
    int t = threadIdx.x, b = blockIdx.x;
    if (b == 0 && t < 64) g[t] = 0.f;   // replaces memset launch

    // P1: per-chunk LDS histogram over 64-node buckets
    for (int k = t; k < NB; k += 256) sm[k] = 0;
    __syncthreads();
    int base = b * CH2;
    int lim = min(E, base + CH2);
    for (int e = base + t; e < lim; e += 256) atomicAdd(&sm[dst[e] >> 6], 1);
    __syncthreads();
    for (int k = t; k < NB; k += 256) histmat[(size_t)b * NB + k] = sm[k];
    grid.sync();

    // P2a: per-bucket column scan over the GB chunks (coalesced, unroll-8)
    int kk = b * 256 + t;
    if (kk < NB) {
        int run = 0;
        for (int c = 0; c < GB; c += 8) {
            int v[8];
#pragma unroll
            for (int u = 0; u < 8; u++) v[u] = histmat[(size_t)(c + u) * NB + kk];
#pragma unroll
            for (int u = 0; u < 8; u++) {
                int x = v[u];
                histmat[(size_t)(c + u) * NB + kk] = run;
                run += x;
            }
        }
        tot[kk] = run;
    }
    grid.sync();

    // P2b: block 0 scans NB bucket totals -> bstart
    if (b == 0) {
        if (t == 0) carry = 0;
        __syncthreads();
        int nchunk = (NB + 255) / 256;
        for (int c = 0; c < nchunk; c++) {
            int idx = c * 256 + t;
            int v = (idx < NB) ? tot[idx] : 0;
            sc[t] = v;
            __syncthreads();
            for (int off = 1; off < 256; off <<= 1) {
                int x = (t >= off) ? sc[t - off] : 0;
                __syncthreads();
                sc[t] += x;
                __syncthreads();
            }
            if (idx < NB) bstart[idx] = sc[t] - v + carry;
            __syncthreads();
            if (t == 0) carry += sc[255];
            __syncthreads();
        }
        if (t == 0) { bstart[NB] = E; offsets[n] = E; }
    }
    grid.sync();

    // P3: scatter into per-(chunk,bucket) contiguous runs (no global atomics)
    for (int k = t; k < NB; k += 256)
        sm[k] = bstart[k] + histmat[(size_t)b * NB + k];
    __syncthreads();
    for (int e = base + t; e < lim; e += 256) {
        int d = dst[e];
        int pos = atomicAdd(&sm[d >> 6], 1);
        staged[pos] = (src[e] << 6) | (d & 63);
    }
    grid.sync();

    // P4: per-bucket counting sort -> node-granular ushort CSR + offsets/dinv
    for (int k = b; k < NB; k += gridDim.x) {
        if (t < 64) cnt[t] = 0;
        __syncthreads();
        int beg = bstart[k], end = bstart[k + 1];
        for (int e = beg + t; e < end; e += 256) atomicAdd(&cnt[staged[e] & 63], 1);
        __syncthreads();
        if (t == 0) {
            int run = 0;
            for (int i = 0; i < 64; i++) { pref[i] = run; run += cnt[i]; }
        }
        __syncthreads();
        if (t < 64) {
            cur[t] = pref[t];
            int node = k * 64 + t;
            if (node < n) {
                offsets[node] = beg + pref[t];
                dinv[node] = 1.0f / sqrtf((float)(cnt[t] + 1));  // + self-loop
            }
        }
        __syncthreads();
        for (int e = beg + t; e < end; e += 256) {
            int pk = staged[e];
            int p = atomicAdd(&cur[pk & 63], 1);
            csr[beg + p] = (unsigned short)(pk >> 6);
        }
        __syncthreads();
    }
}

// Y[i,:] = dinv[i] * (X[i,:] @ W). 16 rows/block, 4 rows/wave: one LDS read
// of W[k][f] feeds 4 FMAs.
__global__ __launch_bounds__(256) void k_gemm_scale(const float* __restrict__ X,
                                                    const float* __restrict__ W,
                                                    const float* __restrict__ dinv,
                                                    float* __restrict__ Y, int n) {
    __shared__ float Ws[64 * 64];
    __shared__ float xs[16][64];
    int t = threadIdx.x, w = t >> 6, f = t & 63;
    const float4* W4 = (const float4*)W;
    float4* Ws4 = (float4*)Ws;
#pragma unroll
    for (int j = 0; j < 4; j++) Ws4[t + 256 * j] = W4[t + 256 * j];
    int r0 = blockIdx.x * 16;
#pragma unroll
    for (int i = 0; i < 4; i++) {
        int r = r0 + w * 4 + i;
        xs[w * 4 + i][f] = (r < n) ? X[(size_t)r * 64 + f] : 0.f;
    }
    __syncthreads();
    float acc[4] = {0.f, 0.f, 0.f, 0.f};
#pragma unroll 8
    for (int k = 0; k < 64; k++) {
        float wv = Ws[k * 64 + f];
#pragma unroll
        for (int i = 0; i < 4; i++) acc[i] += xs[w * 4 + i][k] * wv;
    }
#pragma unroll
    for (int i = 0; i < 4; i++) {
        int r = r0 + w * 4 + i;
        if (r < n) Y[(size_t)r * 64 + f] = dinv[r] * acc[i];
    }
}

// One wave per node (beg/end wave-uniform). lane = (q,c): q=lane>>4 edge
// slot, c=lane&15 float4 col. One dwordx4 instr covers 4 edges x 16 cols;
// unroll-4 => 16 row-gathers in flight per wave. Cross-slot reduce:
// shfl_xor(16,32). POOL: per-block partial mean rows (no global atomics).
template <bool POOL>
__global__ __launch_bounds__(256) void k_aggregate(const float* __restrict__ Y,
                                                   const float* __restrict__ dinv,
                                                   const float* __restrict__ bias,
                                                   const int* __restrict__ offsets,
                                                   const unsigned short* __restrict__ csr,
                                                   float* __restrict__ H,
                                                   float* __restrict__ pbuf, int n) {
    __shared__ float4 sm4[4][16];
    const float4* Y4 = (const float4*)Y;
    int t = threadIdx.x, w = t >> 6, l = t & 63;
    int q = l >> 4, c = l & 15;
    int node = blockIdx.x * 4 + w;
    bool valid = node < n;
    float4 hval = make_float4(0.f, 0.f, 0.f, 0.f);
    if (valid) {
        float4 acc = make_float4(0.f, 0.f, 0.f, 0.f);
        if (q == 0) acc = Y4[(size_t)node * 16 + c];  // self-loop term
        int beg = offsets[node], end = offsets[node + 1];
        for (int j = beg + q; j < end; j += 16) {
#pragma unroll
            for (int u = 0; u < 4; u++) {
                int jj = j + 4 * u;
                bool ok = jj < end;
                float4 v = make_float4(0.f, 0.f, 0.f, 0.f);
                if (ok) {
                    int s = csr[jj];               // uniform within slot
                    v = Y4[(size_t)s * 16 + c];    // 16 lanes x 16B = row
                }
                acc.x += v.x; acc.y += v.y; acc.z += v.z; acc.w += v.w;
            }
        }
        // reduce across the 4 edge slots (lane bits 4,5)
#pragma unroll
        for (int m = 16; m <= 32; m <<= 1) {
            acc.x += __shfl_xor(acc.x, m);
            acc.y += __shfl_xor(acc.y, m);
            acc.z += __shfl_xor(acc.z, m);
            acc.w += __shfl_xor(acc.w, m);
        }
        float dv = dinv[node];
        float4 b4 = ((const float4*)bias)[c];
        hval.x = fmaxf(dv * acc.x + b4.x, 0.f);
        hval.y = fmaxf(dv * acc.y + b4.y, 0.f);
        hval.z = fmaxf(dv * acc.z + b4.z, 0.f);
        hval.w = fmaxf(dv * acc.w + b4.w, 0.f);
        if (!POOL && q == 0) ((float4*)H)[(size_t)node * 16 + c] = hval;
    }
    if (POOL) {
        if (q == 0) sm4[w][c] = valid ? hval : make_float4(0.f, 0.f, 0.f, 0.f);
        __syncthreads();
        if (t < 16) {
            float4 a = sm4[0][t], b = sm4[1][t], d = sm4[2][t], e = sm4[3][t];
            float4 s;
            s.x = (a.x + b.x) + (d.x + e.x);
            s.y = (a.y + b.y) + (d.y + e.y);
            s.z = (a.z + b.z) + (d.z + e.z);
            s.w = (a.w + b.w) + (d.w + e.w);
            ((float4*)pbuf)[(size_t)blockIdx.x * 16 + t] = s;
        }
    }
}

__global__ void k_mean_final(const float* __restrict__ pbuf, float* __restrict__ g,
                             int nrows) {
    __shared__ float part[256];
    int t = threadIdx.x, w = t >> 6, f = t & 63;
    float local = 0.f;
    for (int r = blockIdx.x * 4 + w; r < nrows; r += gridDim.x * 4)
        local += pbuf[(size_t)r * 64 + f];
    part[t] = local;
    __syncthreads();
    if (w == 0) {
        float tot = part[f] + part[64 + f] + part[128 + f] + part[192 + f];
        atomicAdd(&g[f], tot);
    }
}

__global__ void k_readout(const float* __restrict__ g, const float* __restrict__ Wr,
                          const float* __restrict__ br, float* __restrict__ out,
                          float invn) {
    __shared__ float gl[64];
    int t = threadIdx.x;
    if (t < 64) gl[t] = g[t] * invn;
    __syncthreads();
    float acc = br[t];
#pragma unroll
    for (int k = 0; k < 64; k++) acc += gl[k] * Wr[k * 128 + t];
    out[t] = acc;
}

extern "C" void kernel_launch(void* const* d_in, const int* in_sizes, int n_in,
                              void* d_out, int out_size, void* d_ws, size_t ws_size,
                              hipStream_t stream) {
    const float* x  = (const float*)d_in[0];
    const int*   ei = (const int*)d_in[1];   // int32 on device (JAX x64 off)
    const float* W1 = (const float*)d_in[2];
    const float* b1 = (const float*)d_in[3];
    const float* W2 = (const float*)d_in[4];
    const float* b2 = (const float*)d_in[5];
    const float* Wr = (const float*)d_in[6];
    const float* br = (const float*)d_in[7];
    float* out = (float*)d_out;

    int n = in_sizes[0] / 64;   // 50000
    int E = in_sizes[1] / 2;    // 800000
    const int* src = ei;
    const int* dst = ei + E;

    int NB  = (n + 63) / 64;       // 782 buckets of 64 nodes
    int CH2 = (E + GB - 1) / GB;   // edges per build block

    // workspace layout (~31 MB)
    char* p = (char*)d_ws;
    float* y1 = (float*)p;     p += (size_t)n * 64 * sizeof(float);
    float* y2 = (float*)p;     p += (size_t)n * 64 * sizeof(float);
    float* dinv = (float*)p;   p += (size_t)n * sizeof(float);
    float* g = (float*)p;      p += 64 * sizeof(float);
    int* staged = (int*)p;     p += (size_t)E * sizeof(int);
    int* offsets = (int*)p;    p += (size_t)(n + 1) * sizeof(int);
    int* histmat = (int*)p;    p += (size_t)GB * NB * sizeof(int);
    int* tot = (int*)p;        p += (size_t)NB * sizeof(int);
    int* bstart = (int*)p;     p += (size_t)(NB + 1) * sizeof(int);
    unsigned short* csr = (unsigned short*)p; p += (size_t)E * sizeof(unsigned short);

    void* bargs[] = {&src, &dst, &histmat, &tot, &bstart, &staged, &csr,
                     &offsets, &dinv, &g, &E, &n, &NB, &CH2};
    hipLaunchCooperativeKernel((void*)k_build, dim3(GB), dim3(256), bargs, 0, stream);

    int gb = (n + 3) / 4;  // 12500 aggregate blocks (one wave per node)
    k_gemm_scale<<<(n + 15) / 16, 256, 0, stream>>>(x, W1, dinv, y1, n);
    k_aggregate<false><<<gb, 256, 0, stream>>>(y1, dinv, b1, offsets, csr, y2, nullptr, n);
    k_gemm_scale<<<(n + 15) / 16, 256, 0, stream>>>(y2, W2, dinv, y1, n);
    float* pbuf = y2;  // h dead after gemm2 -> per-block partial rows
    k_aggregate<true><<<gb, 256, 0, stream>>>(y1, dinv, b2, offsets, csr, nullptr, pbuf, n);

    k_mean_final<<<64, 256, 0, stream>>>(pbuf, g, gb);
    k_readout<<<1, 128, 0, stream>>>(g, Wr, br, out, 1.0f / (float)n);
}

// Round 11
// 231.103 us; speedup vs baseline: 2.4182x; 1.5884x over previous
//
#include <hip/hip_runtime.h>
#include <math.h>

// SimpleGCN: h1 = relu(GCN(x,W1,b1)); h2 = relu(GCN(h1,W2,b2));
// g = mean(h2, axis=0); out = (g@Wr + br) -> 128 fp32.
// GCN(x,W,b)[d] = dinv[d]*( sum_{s in N(d)} y[s] + y[d] ) + b,
//   y = dinv * (x@W), dinv[i] = (1+indeg[1])^-0.5.
//
// R10 post-mortem: cooperative k_build = 150us — grid.sync's device-scope
// fences flush per-XCD L2s between phases (WRITE 20MB vs 6MB payload);
// separate dispatches ARE the cheap grid barrier on 8-XCD CDNA4. Reverted.
// R11 = R6 pipeline (separate build kernels, wave-per-node aggregate) +
// BF16 feature rows: Y/h1 stored bf16 (fp32 accum). Rows become one
// 128B cache line -> aggregate's random-gather misses halve (FETCH 81->~42MB).
// Mean over 50k nodes shrinks bf16 noise ~224x -> absmax ~1e-5 << 2.73e-3.
// ushort CSR kept.

#define CH 4096    // edges per chunk-block in hist/scatter
#define MAXNB 1024 // NB = ceil(n/64) <= 1024 (n <= 65536)

__device__ __forceinline__ float bf2f(unsigned short u) {
    return __uint_as_float(((unsigned)u) << 16);
}
__device__ __forceinline__ unsigned short f2bf(float x) {
    unsigned b = __float_as_uint(x);
    return (unsigned short)((b + 0x7FFF + ((b >> 16) & 1)) >> 16);  // RNE
}

__global__ __launch_bounds__(256) void k_bucket_hist(const int* __restrict__ dst,
                                                     int* __restrict__ histmat,
                                                     int E, int NB) {
    __shared__ int ih[MAXNB];
    int t = threadIdx.x;
    for (int k = t; k < NB; k += 256) ih[k] = 0;
    __syncthreads();
    int base = blockIdx.x * CH;
    for (int i = 0; i < CH; i += 256) {
        int e = base + i + t;
        if (e < E) atomicAdd(&ih[dst[e] >> 6], 1);
    }
    __syncthreads();
    for (int k = t; k < NB; k += 256) histmat[(size_t)blockIdx.x * NB + k] = ih[k];
}

// thread per bucket: exclusive prefix over chunks in place + total.
__global__ __launch_bounds__(256) void k_colscan(int* __restrict__ histmat,
                                                 int* __restrict__ tot,
                                                 int NB, int nch) {
    int k = blockIdx.x * 256 + threadIdx.x;
    if (k >= NB) return;
    int run = 0;
    int b = 0;
    for (; b + 8 <= nch; b += 8) {
        int v[8];
#pragma unroll
        for (int u = 0; u < 8; u++) v[u] = histmat[(size_t)(b + u) * NB + k];
#pragma unroll
        for (int u = 0; u < 8; u++) {
            int x = v[u];
            histmat[(size_t)(b + u) * NB + k] = run;
            run += x;
        }
    }
    for (; b < nch; b++) {
        int x = histmat[(size_t)b * NB + k];
        histmat[(size_t)b * NB + k] = run;
        run += x;
    }
    tot[k] = run;
}

// single block: exclusive scan of NB (<=1024) totals -> bstart; tails.
__global__ __launch_bounds__(256) void k_scanb(const int* __restrict__ tot,
                                               int* __restrict__ bstart,
                                               int* __restrict__ offsets,
                                               int NB, int E, int n) {
    __shared__ int sc[256];
    __shared__ int carry;
    int t = threadIdx.x;
    if (t == 0) carry = 0;
    __syncthreads();
    int nchunk = (NB + 255) / 256;
    for (int c = 0; c < nchunk; c++) {
        int idx = c * 256 + t;
        int v = (idx < NB) ? tot[idx] : 0;
        sc[t] = v;
        __syncthreads();
        for (int off = 1; off < 256; off <<= 1) {
            int x = (t >= off) ? sc[t - off] : 0;
            __syncthreads();
            sc[t] += x;
            __syncthreads();
        }
        if (idx < NB) bstart[idx] = sc[t] - v + carry;
        __syncthreads();
        if (t == 0) carry += sc[255];
        __syncthreads();
    }
    if (t == 0) { bstart[NB] = E; offsets[n] = E; }
}

__global__ __launch_bounds__(256) void k_bucket_scatter(const int* __restrict__ src,
                                                        const int* __restrict__ dst,
                                                        const int* __restrict__ histmat,
                                                        const int* __restrict__ bstart,
                                                        int* __restrict__ staged,
                                                        int E, int NB) {
    __shared__ int cur[MAXNB];
    int t = threadIdx.x;
    for (int k = t; k < NB; k += 256)
        cur[k] = bstart[k] + histmat[(size_t)blockIdx.x * NB + k];
    __syncthreads();
    int base = blockIdx.x * CH;
    for (int i = 0; i < CH; i += 256) {
        int e = base + i + t;
        if (e < E) {
            int d = dst[e];
            int pos = atomicAdd(&cur[d >> 6], 1);
            staged[pos] = (src[e] << 6) | (d & 63);  // n<=65536 -> fits
        }
    }
}

// one block per bucket: counting-sort staged run into node-granular ushort
// CSR; emit per-node offsets + dinv.
__global__ __launch_bounds__(256) void k_local_sort(const int* __restrict__ staged,
                                                    const int* __restrict__ bstart,
                                                    unsigned short* __restrict__ csr,
                                                    int* __restrict__ offsets,
                                                    float* __restrict__ dinv, int n) {
    __shared__ int cnt[64];
    __shared__ int pos[64];
    __shared__ int cur[64];
    int t = threadIdx.x;
    if (t < 64) cnt[t] = 0;
    __syncthreads();
    int k = blockIdx.x;
    int beg = bstart[k], end = bstart[k + 1];
    for (int e = beg + t; e < end; e += 256) atomicAdd(&cnt[staged[e] & 63], 1);
    __syncthreads();
    if (t == 0) {
        int run = 0;
        for (int i = 0; i < 64; i++) { pos[i] = run; run += cnt[i]; }
    }
    __syncthreads();
    if (t < 64) {
        cur[t] = pos[t];
        int node = k * 64 + t;
        if (node < n) {
            offsets[node] = beg + pos[t];
            dinv[node] = 1.0f / sqrtf((float)(cnt[t] + 1));  // + self-loop
        }
    }
    __syncthreads();
    for (int e = beg + t; e < end; e += 256) {
        int pk = staged[e];
        int p = atomicAdd(&cur[pk & 63], 1);
        csr[beg + p] = (unsigned short)(pk >> 6);
    }
}

// Y[i,:] = dinv[i] * (X[i,:] @ W) stored as BF16 rows (128B = 1 cache line).
// BIN: input X is bf16 (h1 handoff). 16 rows/block, 4 rows/wave.
template <bool BIN>
__global__ __launch_bounds__(256) void k_gemm_scale(const void* __restrict__ Xv,
                                                    const float* __restrict__ W,
                                                    const float* __restrict__ dinv,
                                                    unsigned short* __restrict__ Y, int n) {
    __shared__ float Ws[64 * 64];
    __shared__ float xs[16][64];
    int t = threadIdx.x, w = t >> 6, f = t & 63;
    const float4* W4 = (const float4*)W;
    float4* Ws4 = (float4*)Ws;
#pragma unroll
    for (int j = 0; j < 4; j++) Ws4[t + 256 * j] = W4[t + 256 * j];
    int r0 = blockIdx.x * 16;
#pragma unroll
    for (int i = 0; i < 4; i++) {
        int r = r0 + w * 4 + i;
        float v = 0.f;
        if (r < n)
            v = BIN ? bf2f(((const unsigned short*)Xv)[(size_t)r * 64 + f])
                    : ((const float*)Xv)[(size_t)r * 64 + f];
        xs[w * 4 + i][f] = v;
    }
    __syncthreads();
    float acc[4] = {0.f, 0.f, 0.f, 0.f};
#pragma unroll 8
    for (int k = 0; k < 64; k++) {
        float wv = Ws[k * 64 + f];
#pragma unroll
        for (int i = 0; i < 4; i++) acc[i] += xs[w * 4 + i][k] * wv;
    }
#pragma unroll
    for (int i = 0; i < 4; i++) {
        int r = r0 + w * 4 + i;
        if (r < n) Y[(size_t)r * 64 + f] = f2bf(dinv[r] * acc[i]);
    }
}

// One wave per node (beg/end wave-uniform). lane = (q,c): q=lane>>4 edge
// slot, c=lane&15 covers the row as 16 x ushort4 (8B) -> one dwordx2 instr
// covers 4 edges x 16 cols; unroll-4 => 16 row-gathers (1 line each) in
// flight/wave. fp32 accumulate; cross-slot reduce shfl_xor(16,32).
// POOL: per-block partial mean rows (fp32, no global atomics).
template <bool POOL>
__global__ __launch_bounds__(256) void k_aggregate(const unsigned short* __restrict__ Y,
                                                   const float* __restrict__ dinv,
                                                   const float* __restrict__ bias,
                                                   const int* __restrict__ offsets,
                                                   const unsigned short* __restrict__ csr,
                                                   unsigned short* __restrict__ H,
                                                   float* __restrict__ pbuf, int n) {
    __shared__ float4 sm4[4][16];
    const ushort4* Y4 = (const ushort4*)Y;
    int t = threadIdx.x, w = t >> 6, l = t & 63;
    int q = l >> 4, c = l & 15;
    int node = blockIdx.x * 4 + w;
    bool valid = node < n;
    float4 hval = make_float4(0.f, 0.f, 0.f, 0.f);
    if (valid) {
        float4 acc = make_float4(0.f, 0.f, 0.f, 0.f);
        if (q == 0) {  // self-loop term
            ushort4 u = Y4[(size_t)node * 16 + c];
            acc = make_float4(bf2f(u.x), bf2f(u.y), bf2f(u.z), bf2f(u.w));
        }
        int beg = offsets[node], end = offsets[node + 1];
        for (int j = beg + q; j < end; j += 16) {
#pragma unroll
            for (int u = 0; u < 4; u++) {
                int jj = j + 4 * u;
                if (jj < end) {
                    int s = csr[jj];               // uniform within slot
                    ushort4 v = Y4[(size_t)s * 16 + c];  // 16 lanes x 8B = row
                    acc.x += bf2f(v.x); acc.y += bf2f(v.y);
                    acc.z += bf2f(v.z); acc.w += bf2f(v.w);
                }
            }
        }
        // reduce across the 4 edge slots (lane bits 4,5)
#pragma unroll
        for (int m = 16; m <= 32; m <<= 1) {
            acc.x += __shfl_xor(acc.x, m);
            acc.y += __shfl_xor(acc.y, m);
            acc.z += __shfl_xor(acc.z, m);
            acc.w += __shfl_xor(acc.w, m);
        }
        float dv = dinv[node];
        float4 b4 = ((const float4*)bias)[c];
        hval.x = fmaxf(dv * acc.x + b4.x, 0.f);
        hval.y = fmaxf(dv * acc.y + b4.y, 0.f);
        hval.z = fmaxf(dv * acc.z + b4.z, 0.f);
        hval.w = fmaxf(dv * acc.w + b4.w, 0.f);
        if (!POOL && q == 0) {
            ushort4 o;
            o.x = f2bf(hval.x); o.y = f2bf(hval.y);
            o.z = f2bf(hval.z); o.w = f2bf(hval.w);
            ((ushort4*)H)[(size_t)node * 16 + c] = o;
        }
    }
    if (POOL) {
        if (q == 0) sm4[w][c] = valid ? hval : make_float4(0.f, 0.f, 0.f, 0.f);
        __syncthreads();
        if (t < 16) {
            float4 a = sm4[0][t], b = sm4[1][t], d = sm4[2][t], e = sm4[3][t];
            float4 s;
            s.x = (a.x + b.x) + (d.x + e.x);
            s.y = (a.y + b.y) + (d.y + e.y);
            s.z = (a.z + b.z) + (d.z + e.z);
            s.w = (a.w + b.w) + (d.w + e.w);
            ((float4*)pbuf)[(size_t)blockIdx.x * 16 + t] = s;
        }
    }
}

__global__ void k_mean_final(const float* __restrict__ pbuf, float* __restrict__ g,
                             int nrows) {
    __shared__ float part[256];
    int t = threadIdx.x, w = t >> 6, f = t & 63;
    float local = 0.f;
    for (int r = blockIdx.x * 4 + w; r < nrows; r += gridDim.x * 4)
        local += pbuf[(size_t)r * 64 + f];
    part[t] = local;
    __syncthreads();
    if (w == 0) {
        float tot = part[f] + part[64 + f] + part[128 + f] + part[192 + f];
        atomicAdd(&g[f], tot);
    }
}

__global__ void k_readout(const float* __restrict__ g, const float* __restrict__ Wr,
                          const float* __restrict__ br, float* __restrict__ out,
                          float invn) {
    __shared__ float gl[64];
    int t = threadIdx.x;
    if (t < 64) gl[t] = g[t] * invn;
    __syncthreads();
    float acc = br[t];
#pragma unroll
    for (int k = 0; k < 64; k++) acc += gl[k] * Wr[k * 128 + t];
    out[t] = acc;
}

extern "C" void kernel_launch(void* const* d_in, const int* in_sizes, int n_in,
                              void* d_out, int out_size, void* d_ws, size_t ws_size,
                              hipStream_t stream) {
    const float* x  = (const float*)d_in[0];
    const int*   ei = (const int*)d_in[1];   // int32 on device (JAX x64 off)
    const float* W1 = (const float*)d_in[2];
    const float* b1 = (const float*)d_in[3];
    const float* W2 = (const float*)d_in[4];
    const float* b2 = (const float*)d_in[5];
    const float* Wr = (const float*)d_in[6];
    const float* br = (const float*)d_in[7];
    float* out = (float*)d_out;

    int n = in_sizes[0] / 64;   // 50000
    int E = in_sizes[1] / 2;    // 800000
    const int* src = ei;
    const int* dst = ei + E;

    int NB  = (n + 63) / 64;       // 782 buckets of 64 nodes
    int nch = (E + CH - 1) / CH;   // 196 chunks

    // workspace layout (~25 MB)
    char* p = (char*)d_ws;
    unsigned short* y1 = (unsigned short*)p; p += (size_t)n * 64 * sizeof(unsigned short);
    unsigned short* y2 = (unsigned short*)p; p += (size_t)n * 64 * sizeof(unsigned short);
    float* pbuf = (float*)p;   p += (size_t)((n + 3) / 4) * 64 * sizeof(float);
    float* dinv = (float*)p;   p += (size_t)n * sizeof(float);
    float* g = (float*)p;      p += 64 * sizeof(float);
    int* staged = (int*)p;     p += (size_t)E * sizeof(int);
    int* offsets = (int*)p;    p += (size_t)(n + 1) * sizeof(int);
    int* histmat = (int*)p;    p += (size_t)nch * NB * sizeof(int);
    int* tot = (int*)p;        p += (size_t)NB * sizeof(int);
    int* bstart = (int*)p;     p += (size_t)(NB + 1) * sizeof(int);
    unsigned short* csr = (unsigned short*)p; p += (size_t)E * sizeof(unsigned short);

    hipMemsetAsync(g, 0, 64 * sizeof(float), stream);
    k_bucket_hist<<<nch, 256, 0, stream>>>(dst, histmat, E, NB);
    k_colscan<<<(NB + 255) / 256, 256, 0, stream>>>(histmat, tot, NB, nch);
    k_scanb<<<1, 256, 0, stream>>>(tot, bstart, offsets, NB, E, n);
    k_bucket_scatter<<<nch, 256, 0, stream>>>(src, dst, histmat, bstart, staged, E, NB);
    k_local_sort<<<NB, 256, 0, stream>>>(staged, bstart, csr, offsets, dinv, n);

    int gb = (n + 3) / 4;  // 12500 aggregate blocks (one wave per node)
    k_gemm_scale<false><<<(n + 15) / 16, 256, 0, stream>>>(x, W1, dinv, y1, n);
    k_aggregate<false><<<gb, 256, 0, stream>>>(y1, dinv, b1, offsets, csr, y2, nullptr, n);
    k_gemm_scale<true><<<(n + 15) / 16, 256, 0, stream>>>(y2, W2, dinv, y1, n);
    k_aggregate<true><<<gb, 256, 0, stream>>>(y1, dinv, b2, offsets, csr, nullptr, pbuf, n);

    k_mean_final<<<64, 256, 0, stream>>>(pbuf, g, gb);
    k_readout<<<1, 128, 0, stream>>>(g, Wr, br, out, 1.0f / (float)n);
}

// Round 12
// 229.926 us; speedup vs baseline: 2.4306x; 1.0051x over previous
//
#include <hip/hip_runtime.h>
#include <math.h>

// SimpleGCN: h1 = relu(GCN(x,W1,b1)); h2 = relu(GCN(h1,W2,b2));
// g = mean(h2, axis=0); out = (g@Wr + br) -> 128 fp32.
// GCN(x,W,b)[d] = dinv[d]*( sum_{s in N(d)} y[s] + y[d] ) + b,
//   y = dinv * (x@W), dinv[i] = (1+indeg[i])^-0.5.
//
// R11 post-mortem: wall ~= sum(dispatch) + ~6us/dispatch graph gap; kernel
// sum ~155us over 12 dispatches. R12: 9 dispatches.
//  - colscan+scanb+g-zero merged into ONE single-block 1024-thread kernel
//    (NB=782<=1024: per-thread chunk prefix, in-LDS block scan -> bstart).
//  - gemm2 fused into agg1 (R7-style epilogue, R6/R11-style gather kept
//    verbatim: wave-per-node, ushort4 slot gather): h1 row -> LDS, one
//    syncthreads, each lane computes one output feature vs LDS W2.
//  - bf16 feature rows (128B/row), ushort CSR, pbuf+mean_final kept.

#define CH 4096    // edges per chunk-block in hist/scatter
#define MAXNB 1024 // NB = ceil(n/64) <= 1024 (n <= 65536)

__device__ __forceinline__ float bf2f(unsigned short u) {
    return __uint_as_float(((unsigned)u) << 16);
}
__device__ __forceinline__ unsigned short f2bf(float x) {
    unsigned b = __float_as_uint(x);
    return (unsigned short)((b + 0x7FFF + ((b >> 16) & 1)) >> 16);  // RNE
}

__global__ __launch_bounds__(256) void k_bucket_hist(const int* __restrict__ dst,
                                                     int* __restrict__ histmat,
                                                     int E, int NB) {
    __shared__ int ih[MAXNB];
    int t = threadIdx.x;
    for (int k = t; k < NB; k += 256) ih[k] = 0;
    __syncthreads();
    int base = blockIdx.x * CH;
    for (int i = 0; i < CH; i += 256) {
        int e = base + i + t;
        if (e < E) atomicAdd(&ih[dst[e] >> 6], 1);
    }
    __syncthreads();
    for (int k = t; k < NB; k += 256) histmat[(size_t)blockIdx.x * NB + k] = ih[k];
}

// ONE block, 1024 threads (thread = bucket, NB<=1024): per-bucket exclusive
// prefix over chunks (in-place in histmat, coalesced, unroll-8), then an
// in-LDS Hillis-Steele scan of bucket totals -> bstart. Also zeroes g.
__global__ __launch_bounds__(1024) void k_scan(int* __restrict__ histmat,
                                               int* __restrict__ bstart,
                                               int* __restrict__ offsets,
                                               float* __restrict__ g,
                                               int NB, int nch, int E, int n) {
    __shared__ int sc[1024];
    int t = threadIdx.x;
    int run = 0;
    if (t < NB) {
        int b = 0;
        for (; b + 8 <= nch; b += 8) {
            int v[8];
#pragma unroll
            for (int u = 0; u < 8; u++) v[u] = histmat[(size_t)(b + u) * NB + t];
#pragma unroll
            for (int u = 0; u < 8; u++) {
                int x = v[u];
                histmat[(size_t)(b + u) * NB + t] = run;
                run += x;
            }
        }
        for (; b < nch; b++) {
            int x = histmat[(size_t)b * NB + t];
            histmat[(size_t)b * NB + t] = run;
            run += x;
        }
    }
    sc[t] = (t < NB) ? run : 0;
    __syncthreads();
    for (int off = 1; off < 1024; off <<= 1) {
        int x = (t >= off) ? sc[t - off] : 0;
        __syncthreads();
        sc[t] += x;
        __syncthreads();
    }
    if (t < NB) bstart[t] = sc[t] - run;  // exclusive
    if (t == 0) { bstart[NB] = E; offsets[n] = E; }
    if (t < 64) g[t] = 0.f;
}

__global__ __launch_bounds__(256) void k_bucket_scatter(const int* __restrict__ src,
                                                        const int* __restrict__ dst,
                                                        const int* __restrict__ histmat,
                                                        const int* __restrict__ bstart,
                                                        int* __restrict__ staged,
                                                        int E, int NB) {
    __shared__ int cur[MAXNB];
    int t = threadIdx.x;
    for (int k = t; k < NB; k += 256)
        cur[k] = bstart[k] + histmat[(size_t)blockIdx.x * NB + k];
    __syncthreads();
    int base = blockIdx.x * CH;
    for (int i = 0; i < CH; i += 256) {
        int e = base + i + t;
        if (e < E) {
            int d = dst[e];
            int pos = atomicAdd(&cur[d >> 6], 1);
            staged[pos] = (src[e] << 6) | (d & 63);  // n<=65536 -> fits
        }
    }
}

// one block per bucket: counting-sort staged run into node-granular ushort
// CSR; emit per-node offsets + dinv.
__global__ __launch_bounds__(256) void k_local_sort(const int* __restrict__ staged,
                                                    const int* __restrict__ bstart,
                                                    unsigned short* __restrict__ csr,
                                                    int* __restrict__ offsets,
                                                    float* __restrict__ dinv, int n) {
    __shared__ int cnt[64];
    __shared__ int pos[64];
    __shared__ int cur[64];
    int t = threadIdx.x;
    if (t < 64) cnt[t] = 0;
    __syncthreads();
    int k = blockIdx.x;
    int beg = bstart[k], end = bstart[k + 1];
    for (int e = beg + t; e < end; e += 256) atomicAdd(&cnt[staged[e] & 63], 1);
    __syncthreads();
    if (t == 0) {
        int run = 0;
        for (int i = 0; i < 64; i++) { pos[i] = run; run += cnt[i]; }
    }
    __syncthreads();
    if (t < 64) {
        cur[t] = pos[t];
        int node = k * 64 + t;
        if (node < n) {
            offsets[node] = beg + pos[t];
            dinv[node] = 1.0f / sqrtf((float)(cnt[t] + 1));  // + self-loop
        }
    }
    __syncthreads();
    for (int e = beg + t; e < end; e += 256) {
        int pk = staged[e];
        int p = atomicAdd(&cur[pk & 63], 1);
        csr[beg + p] = (unsigned short)(pk >> 6);
    }
}

// y1[i,:] = dinv[i] * (X[i,:] @ W) stored as bf16 rows (128B = 1 line).
__global__ __launch_bounds__(256) void k_gemm_scale(const float* __restrict__ X,
                                                    const float* __restrict__ W,
                                                    const float* __restrict__ dinv,
                                                    unsigned short* __restrict__ Y, int n) {
    __shared__ float Ws[64 * 64];
    __shared__ float xs[16][64];
    int t = threadIdx.x, w = t >> 6, f = t & 63;
    const float4* W4 = (const float4*)W;
    float4* Ws4 = (float4*)Ws;
#pragma unroll
    for (int j = 0; j < 4; j++) Ws4[t + 256 * j] = W4[t + 256 * j];
    int r0 = blockIdx.x * 16;
#pragma unroll
    for (int i = 0; i < 4; i++) {
        int r = r0 + w * 4 + i;
        xs[w * 4 + i][f] = (r < n) ? X[(size_t)r * 64 + f] : 0.f;
    }
    __syncthreads();
    float acc[4] = {0.f, 0.f, 0.f, 0.f};
#pragma unroll 8
    for (int k = 0; k < 64; k++) {
        float wv = Ws[k * 64 + f];
#pragma unroll
        for (int i = 0; i < 4; i++) acc[i] += xs[w * 4 + i][k] * wv;
    }
#pragma unroll
    for (int i = 0; i < 4; i++) {
        int r = r0 + w * 4 + i;
        if (r < n) Y[(size_t)r * 64 + f] = f2bf(dinv[r] * acc[i]);
    }
}

// Layer-1 aggregate + fused GEMM2. Gather identical to R11: one wave per
// node (beg/end wave-uniform), lane=(q,c), ushort4 slot loads, unroll-4,
// shfl_xor(16,32) reduce, fp32 h. Epilogue: q==0 lanes park h row in LDS,
// one __syncthreads, lane l computes y2[node][l] = dinv*(h @ W2[:,l]) from
// LDS W2 (h read is wave-broadcast, W2 read is 2-lanes/bank -> free).
__global__ __launch_bounds__(256) void k_agg_fuse(const unsigned short* __restrict__ Y,
                                                  const float* __restrict__ dinv,
                                                  const float* __restrict__ bias,
                                                  const int* __restrict__ offsets,
                                                  const unsigned short* __restrict__ csr,
                                                  const float* __restrict__ W2,
                                                  unsigned short* __restrict__ Yout, int n) {
    __shared__ float Ws[64 * 64];   // 16 KB
    __shared__ float hs[4][64];     // 1 KB
    const ushort4* Y4 = (const ushort4*)Y;
    int t = threadIdx.x, w = t >> 6, l = t & 63;
    int q = l >> 4, c = l & 15;
    {
        const float4* W4 = (const float4*)W2;
        float4* Ws4 = (float4*)Ws;
#pragma unroll
        for (int j = 0; j < 4; j++) Ws4[t + 256 * j] = W4[t + 256 * j];
    }
    int node = blockIdx.x * 4 + w;
    bool valid = node < n;
    float4 hval = make_float4(0.f, 0.f, 0.f, 0.f);
    float dv = 0.f;
    if (valid) {
        float4 acc = make_float4(0.f, 0.f, 0.f, 0.f);
        if (q == 0) {  // self-loop term
            ushort4 u = Y4[(size_t)node * 16 + c];
            acc = make_float4(bf2f(u.x), bf2f(u.y), bf2f(u.z), bf2f(u.w));
        }
        int beg = offsets[node], end = offsets[node + 1];
        for (int j = beg + q; j < end; j += 16) {
#pragma unroll
            for (int u = 0; u < 4; u++) {
                int jj = j + 4 * u;
                if (jj < end) {
                    int s = csr[jj];                     // uniform within slot
                    ushort4 v = Y4[(size_t)s * 16 + c];  // 16 lanes x 8B = row
                    acc.x += bf2f(v.x); acc.y += bf2f(v.y);
                    acc.z += bf2f(v.z); acc.w += bf2f(v.w);
                }
            }
        }
#pragma unroll
        for (int m = 16; m <= 32; m <<= 1) {
            acc.x += __shfl_xor(acc.x, m);
            acc.y += __shfl_xor(acc.y, m);
            acc.z += __shfl_xor(acc.z, m);
            acc.w += __shfl_xor(acc.w, m);
        }
        dv = dinv[node];
        float4 b4 = ((const float4*)bias)[c];
        hval.x = fmaxf(dv * acc.x + b4.x, 0.f);
        hval.y = fmaxf(dv * acc.y + b4.y, 0.f);
        hval.z = fmaxf(dv * acc.z + b4.z, 0.f);
        hval.w = fmaxf(dv * acc.w + b4.w, 0.f);
    }
    if (q == 0) ((float4*)hs[w])[c] = hval;  // zeros if invalid
    __syncthreads();
    if (valid) {
        float acc2 = 0.f;
#pragma unroll
        for (int m = 0; m < 16; m++) {
            float4 h4 = ((const float4*)hs[w])[m];   // wave-broadcast
            acc2 += h4.x * Ws[(4 * m + 0) * 64 + l] + h4.y * Ws[(4 * m + 1) * 64 + l]
                  + h4.z * Ws[(4 * m + 2) * 64 + l] + h4.w * Ws[(4 * m + 3) * 64 + l];
        }
        Yout[(size_t)node * 64 + l] = f2bf(dv * acc2);
    }
}

// Layer-2 aggregate + per-block partial mean rows (R11 POOL path).
__global__ __launch_bounds__(256) void k_agg_pool(const unsigned short* __restrict__ Y,
                                                  const float* __restrict__ dinv,
                                                  const float* __restrict__ bias,
                                                  const int* __restrict__ offsets,
                                                  const unsigned short* __restrict__ csr,
                                                  float* __restrict__ pbuf, int n) {
    __shared__ float4 sm4[4][16];
    const ushort4* Y4 = (const ushort4*)Y;
    int t = threadIdx.x, w = t >> 6, l = t & 63;
    int q = l >> 4, c = l & 15;
    int node = blockIdx.x * 4 + w;
    bool valid = node < n;
    float4 hval = make_float4(0.f, 0.f, 0.f, 0.f);
    if (valid) {
        float4 acc = make_float4(0.f, 0.f, 0.f, 0.f);
        if (q == 0) {
            ushort4 u = Y4[(size_t)node * 16 + c];
            acc = make_float4(bf2f(u.x), bf2f(u.y), bf2f(u.z), bf2f(u.w));
        }
        int beg = offsets[node], end = offsets[node + 1];
        for (int j = beg + q; j < end; j += 16) {
#pragma unroll
            for (int u = 0; u < 4; u++) {
                int jj = j + 4 * u;
                if (jj < end) {
                    int s = csr[jj];
                    ushort4 v = Y4[(size_t)s * 16 + c];
                    acc.x += bf2f(v.x); acc.y += bf2f(v.y);
                    acc.z += bf2f(v.z); acc.w += bf2f(v.w);
                }
            }
        }
#pragma unroll
        for (int m = 16; m <= 32; m <<= 1) {
            acc.x += __shfl_xor(acc.x, m);
            acc.y += __shfl_xor(acc.y, m);
            acc.z += __shfl_xor(acc.z, m);
            acc.w += __shfl_xor(acc.w, m);
        }
        float dv = dinv[node];
        float4 b4 = ((const float4*)bias)[c];
        hval.x = fmaxf(dv * acc.x + b4.x, 0.f);
        hval.y = fmaxf(dv * acc.y + b4.y, 0.f);
        hval.z = fmaxf(dv * acc.z + b4.z, 0.f);
        hval.w = fmaxf(dv * acc.w + b4.w, 0.f);
    }
    if (q == 0) sm4[w][c] = valid ? hval : make_float4(0.f, 0.f, 0.f, 0.f);
    __syncthreads();
    if (t < 16) {
        float4 a = sm4[0][t], b = sm4[1][t], d = sm4[2][t], e = sm4[3][t];
        float4 s;
        s.x = (a.x + b.x) + (d.x + e.x);
        s.y = (a.y + b.y) + (d.y + e.y);
        s.z = (a.z + b.z) + (d.z + e.z);
        s.w = (a.w + b.w) + (d.w + e.w);
        ((float4*)pbuf)[(size_t)blockIdx.x * 16 + t] = s;
    }
}

__global__ void k_mean_final(const float* __restrict__ pbuf, float* __restrict__ g,
                             int nrows) {
    __shared__ float part[256];
    int t = threadIdx.x, w = t >> 6, f = t & 63;
    float local = 0.f;
    for (int r = blockIdx.x * 4 + w; r < nrows; r += gridDim.x * 4)
        local += pbuf[(size_t)r * 64 + f];
    part[t] = local;
    __syncthreads();
    if (w == 0) {
        float tot = part[f] + part[64 + f] + part[128 + f] + part[192 + f];
        atomicAdd(&g[f], tot);
    }
}

__global__ void k_readout(const float* __restrict__ g, const float* __restrict__ Wr,
                          const float* __restrict__ br, float* __restrict__ out,
                          float invn) {
    __shared__ float gl[64];
    int t = threadIdx.x;
    if (t < 64) gl[t] = g[t] * invn;
    __syncthreads();
    float acc = br[t];
#pragma unroll
    for (int k = 0; k < 64; k++) acc += gl[k] * Wr[k * 128 + t];
    out[t] = acc;
}

extern "C" void kernel_launch(void* const* d_in, const int* in_sizes, int n_in,
                              void* d_out, int out_size, void* d_ws, size_t ws_size,
                              hipStream_t stream) {
    const float* x  = (const float*)d_in[0];
    const int*   ei = (const int*)d_in[1];   // int32 on device (JAX x64 off)
    const float* W1 = (const float*)d_in[2];
    const float* b1 = (const float*)d_in[3];
    const float* W2 = (const float*)d_in[4];
    const float* b2 = (const float*)d_in[5];
    const float* Wr = (const float*)d_in[6];
    const float* br = (const float*)d_in[7];
    float* out = (float*)d_out;

    int n = in_sizes[0] / 64;   // 50000
    int E = in_sizes[1] / 2;    // 800000
    const int* src = ei;
    const int* dst = ei + E;

    int NB  = (n + 63) / 64;       // 782 buckets of 64 nodes
    int nch = (E + CH - 1) / CH;   // 196 chunks

    // workspace layout (~22 MB)
    char* p = (char*)d_ws;
    unsigned short* y1 = (unsigned short*)p; p += (size_t)n * 64 * sizeof(unsigned short);
    unsigned short* y2 = (unsigned short*)p; p += (size_t)n * 64 * sizeof(unsigned short);
    float* pbuf = (float*)p;   p += (size_t)((n + 3) / 4) * 64 * sizeof(float);
    float* dinv = (float*)p;   p += (size_t)n * sizeof(float);
    float* g = (float*)p;      p += 64 * sizeof(float);
    int* staged = (int*)p;     p += (size_t)E * sizeof(int);
    int* offsets = (int*)p;    p += (size_t)(n + 1) * sizeof(int);
    int* histmat = (int*)p;    p += (size_t)nch * NB * sizeof(int);
    int* bstart = (int*)p;     p += (size_t)(NB + 1) * sizeof(int);
    unsigned short* csr = (unsigned short*)p; p += (size_t)E * sizeof(unsigned short);

    k_bucket_hist<<<nch, 256, 0, stream>>>(dst, histmat, E, NB);
    k_scan<<<1, 1024, 0, stream>>>(histmat, bstart, offsets, g, NB, nch, E, n);
    k_bucket_scatter<<<nch, 256, 0, stream>>>(src, dst, histmat, bstart, staged, E, NB);
    k_local_sort<<<NB, 256, 0, stream>>>(staged, bstart, csr, offsets, dinv, n);

    int gb = (n + 3) / 4;  // 12500 aggregate blocks (one wave per node)
    k_gemm_scale<<<(n + 15) / 16, 256, 0, stream>>>(x, W1, dinv, y1, n);
    k_agg_fuse<<<gb, 256, 0, stream>>>(y1, dinv, b1, offsets, csr, W2, y2, n);
    k_agg_pool<<<gb, 256, 0, stream>>>(y2, dinv, b2, offsets, csr, pbuf, n);

    k_mean_final<<<64, 256, 0, stream>>>(pbuf, g, gb);
    k_readout<<<1, 128, 0, stream>>>(g, Wr, br, out, 1.0f / (float)n);
}